// Round 3
// baseline (4999.789 us; speedup 1.0000x reference)
//
#include <hip/hip_runtime.h>
#include <math.h>

constexpr int Bn = 2, Tn = 1024, NHh = 12, HD = 64, D2 = 32, Dm = 768, FF = 3072;
constexpr int BT = Bn * Tn;                 // 2048
constexpr float CN_EPS  = 1e-8f;
constexpr float RMS_EPS = 1.1920929e-07f;

// ---------------------------------------------------------------- small kernels

__global__ void rope_tables_k(float* __restrict__ cosT, float* __restrict__ sinT) {
  int i = blockIdx.x * 256 + threadIdx.x;
  if (i < Tn * D2) {
    int t = i >> 5, j = i & 31;
    float inv = powf(10000.f, -(float)(2 * j) / (float)HD);
    float f = (float)t * inv;
    cosT[i] = cosf(f);
    sinT[i] = sinf(f);
  }
}

__global__ void embed_k(const int* __restrict__ idx, const float* __restrict__ wte,
                        float* __restrict__ xr, float* __restrict__ xi) {
  int i = blockIdx.x * 256 + threadIdx.x;
  if (i < BT * Dm) {
    int row = i / Dm, c = i - row * Dm;
    xr[i] = wte[(size_t)idx[row] * Dm + c];
    xi[i] = 0.f;
  }
}

// complex_norm over D: scale = rsqrt(mean(xr^2+xi^2) + CN_EPS + RMS_EPS)
__global__ __launch_bounds__(256) void cnorm_k(const float* __restrict__ xr, const float* __restrict__ xi,
                                               float* __restrict__ onr, float* __restrict__ oni) {
  int row = blockIdx.x;
  const float* pr = xr + (size_t)row * Dm;
  const float* pi = xi + (size_t)row * Dm;
  float a[3], b[3];
  float ss = 0.f;
#pragma unroll
  for (int j = 0; j < 3; ++j) {
    int c = threadIdx.x + j * 256;
    a[j] = pr[c]; b[j] = pi[c];
    ss += a[j] * a[j] + b[j] * b[j];
  }
#pragma unroll
  for (int d = 32; d; d >>= 1) ss += __shfl_xor(ss, d);
  __shared__ float red[4];
  int wave = threadIdx.x >> 6, lane = threadIdx.x & 63;
  if (lane == 0) red[wave] = ss;
  __syncthreads();
  float tot = red[0] + red[1] + red[2] + red[3];
  float inv = rsqrtf(tot * (1.f / Dm) + CN_EPS + RMS_EPS);
#pragma unroll
  for (int j = 0; j < 3; ++j) {
    int c = threadIdx.x + j * 256;
    onr[(size_t)row * Dm + c] = a[j] * inv;
    oni[(size_t)row * Dm + c] = b[j] * inv;
  }
}

// Batched QKV prep: rope(first half) + complex_norm over HD + transpose
// (B,T,D)->(B,NH,T,HD). blockIdx.y selects {0:q,1:k,2:v}; v skips rope+norm.
__global__ __launch_bounds__(256) void qkv_prep_k(
    const float* __restrict__ aqr, const float* __restrict__ aqi,
    const float* __restrict__ akr, const float* __restrict__ aki,
    const float* __restrict__ avr, const float* __restrict__ avi,
    float* __restrict__ qR, float* __restrict__ qI,
    float* __restrict__ kR, float* __restrict__ kI,
    float* __restrict__ vR, float* __restrict__ vI,
    const float* __restrict__ cosT, const float* __restrict__ sinT) {
  const int which = blockIdx.y;
  const float* inr = (which == 0) ? aqr : (which == 1) ? akr : avr;
  const float* ini = (which == 0) ? aqi : (which == 1) ? aki : avi;
  float* outr = (which == 0) ? qR : (which == 1) ? kR : vR;
  float* outi = (which == 0) ? qI : (which == 1) ? kI : vI;

  int gid  = blockIdx.x * 4 + (threadIdx.x >> 6);   // (b,t,h) item, one wave each
  int lane = threadIdx.x & 63;
  int h  = gid % NHh;
  int bt = gid / NHh;
  int t  = bt & (Tn - 1);
  int b  = bt >> 10;
  size_t src = (size_t)bt * Dm + h * HD + lane;
  float xr = inr[src], xi = ini[src];
  if (which != 2) {
    if (lane < D2) {
      float c = cosT[t * D2 + lane], s = sinT[t * D2 + lane];
      float nr = xr * c - xi * s;
      xi = xr * s + xi * c;
      xr = nr;
    }
    float ss = xr * xr + xi * xi;
#pragma unroll
    for (int d = 32; d; d >>= 1) ss += __shfl_xor(ss, d);
    float inv = rsqrtf(ss * (1.f / HD) + CN_EPS + RMS_EPS);
    xr *= inv; xi *= inv;
  }
  size_t dst = ((size_t)(b * NHh + h) * Tn + t) * HD + lane;
  outr[dst] = xr;
  outi[dst] = xi;
}

__global__ void mlp_pre_k(const float* __restrict__ xrn, const float* __restrict__ xin,
                          float* __restrict__ r) {
  int i = blockIdx.x * 256 + threadIdx.x;
  if (i < BT * Dm)
    r[i] = sqrtf(xrn[i] * xrn[i] + xin[i] * xin[i] + CN_EPS);
}

__global__ void mlp_post_k(const float* __restrict__ rb, const float* __restrict__ delta,
                           const float* __restrict__ xrn, const float* __restrict__ xin,
                           float* __restrict__ xr, float* __restrict__ xi) {
  int i = blockIdx.x * 256 + threadIdx.x;
  if (i < BT * Dm) {
    float r  = rb[i];
    float z  = r + delta[i];
    float rn = (z > 20.f) ? z : log1pf(expf(z));
    float s  = (rn - r) / r;
    xr[i] += xrn[i] * s;
    xi[i] += xin[i] * s;
  }
}

// ---------------------------------------------------------------- GEMM (fp32, C = A @ B^T)
// A: MxK row-major, B: NxK row-major. 128x128 tile, BK=16, 256 thr, 8x8/thread.
// Requires M%128==0, N%128==0, K%16==0 (holds for all call sites).

template<int EPI, bool ACC>   // EPI: 0 none, 1 relu^2
__global__ __launch_bounds__(256) void gemm_nt_k(const float* __restrict__ A, const float* __restrict__ B,
                                                 float* __restrict__ C, int M, int N, int K) {
  __shared__ alignas(16) float As[16][132];
  __shared__ alignas(16) float Bs[16][132];
  const int row0 = blockIdx.y * 128, col0 = blockIdx.x * 128;
  const int tid = threadIdx.x;
  const int tx = tid & 15, ty = tid >> 4;          // 16x16 thread grid
  const int lr = tid >> 1, lk = (tid & 1) * 8;     // staging: 128 rows x 16 k, 8 floats/thread/matrix
  float acc[8][8] = {};
  for (int k0 = 0; k0 < K; k0 += 16) {
    __syncthreads();
    {
      float4 a0 = *(const float4*)&A[(size_t)(row0 + lr) * K + k0 + lk];
      float4 a1 = *(const float4*)&A[(size_t)(row0 + lr) * K + k0 + lk + 4];
      float4 b0 = *(const float4*)&B[(size_t)(col0 + lr) * K + k0 + lk];
      float4 b1 = *(const float4*)&B[(size_t)(col0 + lr) * K + k0 + lk + 4];
      As[lk + 0][lr] = a0.x; As[lk + 1][lr] = a0.y; As[lk + 2][lr] = a0.z; As[lk + 3][lr] = a0.w;
      As[lk + 4][lr] = a1.x; As[lk + 5][lr] = a1.y; As[lk + 6][lr] = a1.z; As[lk + 7][lr] = a1.w;
      Bs[lk + 0][lr] = b0.x; Bs[lk + 1][lr] = b0.y; Bs[lk + 2][lr] = b0.z; Bs[lk + 3][lr] = b0.w;
      Bs[lk + 4][lr] = b1.x; Bs[lk + 5][lr] = b1.y; Bs[lk + 6][lr] = b1.z; Bs[lk + 7][lr] = b1.w;
    }
    __syncthreads();
#pragma unroll
    for (int kk = 0; kk < 16; ++kk) {
      float4 aA = *(const float4*)&As[kk][ty * 4];
      float4 aB = *(const float4*)&As[kk][64 + ty * 4];
      float4 bA = *(const float4*)&Bs[kk][tx * 4];
      float4 bB = *(const float4*)&Bs[kk][64 + tx * 4];
      float av[8] = {aA.x, aA.y, aA.z, aA.w, aB.x, aB.y, aB.z, aB.w};
      float bv[8] = {bA.x, bA.y, bA.z, bA.w, bB.x, bB.y, bB.z, bB.w};
#pragma unroll
      for (int i = 0; i < 8; ++i)
#pragma unroll
        for (int j = 0; j < 8; ++j) acc[i][j] += av[i] * bv[j];
    }
  }
#pragma unroll
  for (int i = 0; i < 8; ++i) {
    const int r = row0 + ((i < 4) ? (ty * 4 + i) : (64 + ty * 4 + i - 4));
#pragma unroll
    for (int j = 0; j < 8; ++j) {
      const int c = col0 + ((j < 4) ? (tx * 4 + j) : (64 + tx * 4 + j - 4));
      size_t o = (size_t)r * N + c;
      float v = acc[i][j];
      if (EPI == 1) { v = fmaxf(v, 0.f); v = v * v; }
      if (ACC) C[o] += v; else C[o] = v;
    }
  }
}

// Complex GEMM core: Or = Ar@Br^T - Ai@Bi^T, Oi = Ar@Bi^T + Ai@Br^T (CW)
//                    Or = Ar@Br^T,            Oi = Ai@Br^T          (!CW)
// 64x64 tile, BK=16, 256 thr, 4x4/thread.
template<bool CW, bool ACC>
__device__ __forceinline__ void cgemm_body(const float* __restrict__ Ar, const float* __restrict__ Ai,
                                           const float* __restrict__ Bw,
                                           float* __restrict__ Cr, float* __restrict__ Ci,
                                           int M, int N, int K, int bx, int by) {
  __shared__ alignas(16) float Asr[16][68];
  __shared__ alignas(16) float Asi[16][68];
  __shared__ alignas(16) float Bsr[16][68];
  __shared__ alignas(16) float Bsi[16][68];
  const int row0 = by * 64, col0 = bx * 64;
  const int tid = threadIdx.x;
  const int tx = tid & 15, ty = tid >> 4;
  const int lr = tid >> 2, lk = (tid & 3) * 4;
  const float* Br = Bw;
  const float* Bi = Bw + (size_t)N * K;
  float acr[4][4] = {};
  float aci[4][4] = {};
  for (int k0 = 0; k0 < K; k0 += 16) {
    __syncthreads();
    {
      float4 a = *(const float4*)&Ar[(size_t)(row0 + lr) * K + k0 + lk];
      float4 b = *(const float4*)&Ai[(size_t)(row0 + lr) * K + k0 + lk];
      float4 c = *(const float4*)&Br[(size_t)(col0 + lr) * K + k0 + lk];
      Asr[lk + 0][lr] = a.x; Asr[lk + 1][lr] = a.y; Asr[lk + 2][lr] = a.z; Asr[lk + 3][lr] = a.w;
      Asi[lk + 0][lr] = b.x; Asi[lk + 1][lr] = b.y; Asi[lk + 2][lr] = b.z; Asi[lk + 3][lr] = b.w;
      Bsr[lk + 0][lr] = c.x; Bsr[lk + 1][lr] = c.y; Bsr[lk + 2][lr] = c.z; Bsr[lk + 3][lr] = c.w;
      if (CW) {
        float4 d = *(const float4*)&Bi[(size_t)(col0 + lr) * K + k0 + lk];
        Bsi[lk + 0][lr] = d.x; Bsi[lk + 1][lr] = d.y; Bsi[lk + 2][lr] = d.z; Bsi[lk + 3][lr] = d.w;
      }
    }
    __syncthreads();
#pragma unroll
    for (int kk = 0; kk < 16; ++kk) {
      float4 a4 = *(const float4*)&Asr[kk][ty * 4];
      float4 i4 = *(const float4*)&Asi[kk][ty * 4];
      float4 b4 = *(const float4*)&Bsr[kk][tx * 4];
      float arv[4] = {a4.x, a4.y, a4.z, a4.w};
      float aiv[4] = {i4.x, i4.y, i4.z, i4.w};
      float brv[4] = {b4.x, b4.y, b4.z, b4.w};
      if (CW) {
        float4 c4 = *(const float4*)&Bsi[kk][tx * 4];
        float biv[4] = {c4.x, c4.y, c4.z, c4.w};
#pragma unroll
        for (int i = 0; i < 4; ++i)
#pragma unroll
          for (int j = 0; j < 4; ++j) {
            acr[i][j] += arv[i] * brv[j] - aiv[i] * biv[j];
            aci[i][j] += arv[i] * biv[j] + aiv[i] * brv[j];
          }
      } else {
#pragma unroll
        for (int i = 0; i < 4; ++i)
#pragma unroll
          for (int j = 0; j < 4; ++j) {
            acr[i][j] += arv[i] * brv[j];
            aci[i][j] += aiv[i] * brv[j];
          }
      }
    }
  }
#pragma unroll
  for (int i = 0; i < 4; ++i)
#pragma unroll
    for (int j = 0; j < 4; ++j) {
      size_t o = (size_t)(row0 + ty * 4 + i) * N + col0 + tx * 4 + j;
      if (ACC) { Cr[o] += acr[i][j]; Ci[o] += aci[i][j]; }
      else     { Cr[o]  = acr[i][j]; Ci[o]  = aci[i][j]; }
    }
}

template<bool CW, bool ACC>
__global__ __launch_bounds__(256) void cgemm_nt_k(const float* __restrict__ Ar, const float* __restrict__ Ai,
                                                  const float* __restrict__ Bw,
                                                  float* __restrict__ Cr, float* __restrict__ Ci,
                                                  int M, int N, int K) {
  cgemm_body<CW, ACC>(Ar, Ai, Bw, Cr, Ci, M, N, K, blockIdx.x, blockIdx.y);
}

// Batched QKV complex GEMM: blockIdx.z selects {0:Wq,1:Wk,2:Wv} + its output pair.
__global__ __launch_bounds__(256) void cgemm_qkv_k(
    const float* __restrict__ Ar, const float* __restrict__ Ai,
    const float* __restrict__ Wq, const float* __restrict__ Wk, const float* __restrict__ Wv,
    float* __restrict__ qr, float* __restrict__ qi,
    float* __restrict__ kr, float* __restrict__ ki,
    float* __restrict__ vr, float* __restrict__ vi,
    int M, int N, int K) {
  const int z = blockIdx.z;
  const float* Bw = (z == 0) ? Wq : (z == 1) ? Wk : Wv;
  float* Cr = (z == 0) ? qr : (z == 1) ? kr : vr;
  float* Ci = (z == 0) ? qi : (z == 1) ? ki : vi;
  cgemm_body<true, false>(Ar, Ai, Bw, Cr, Ci, M, N, K, blockIdx.x, blockIdx.y);
}

// ---------------------------------------------------------------- attention (flash-style, complex scores)
// Inputs in (B,NH,T,HD). Softmax over ALL T positions: masked ones contribute
// exp(sqrt(CN_EPS) - m) to denominator; unprocessed ranges added analytically.
// Block: 4 waves x 4 queries = 16 query rows. Key chunk = 32.

__global__ __launch_bounds__(256) void attn_k(
    const float* __restrict__ qr, const float* __restrict__ qi,
    const float* __restrict__ kr, const float* __restrict__ ki,
    const float* __restrict__ vr, const float* __restrict__ vi,
    float* __restrict__ dzr, float* __restrict__ dzi, int W) {
  const int bh = blockIdx.x;          // b*NH + h
  const int t0 = blockIdx.y * 16;
  const int b = bh / NHh, h = bh % NHh;
  const int tid = threadIdx.x;
  const int wave = tid >> 6, lane = tid & 63;
  const int kslot = lane & 31, ehalf = lane >> 5;
  const int wq0 = wave * 4;

  __shared__ alignas(16) float2 kv[32][66];   // (kr,ki), padded row
  __shared__ alignas(16) float2 vv[32][64];   // (vr,vi)
  __shared__ alignas(16) float2 qsh[16][64];  // (qr,qi)
  __shared__ float2 ps[16][32];               // (p*sr, p*si) per (q,key)

  const size_t base = (size_t)bh * Tn * HD;

  for (int i = tid; i < 16 * 64; i += 256) {
    int q = i >> 6, e = i & 63;
    size_t g = base + (size_t)(t0 + q) * HD + e;
    qsh[q][e] = make_float2(qr[g], qi[g]);
  }

  float m[4], l[4], ar_[4], ai_[4];
#pragma unroll
  for (int q = 0; q < 4; ++q) { m[q] = -1e30f; l[q] = 0.f; ar_[q] = 0.f; ai_[q] = 0.f; }

  int S0 = 0;
  { int s = t0 - W + 1; if (s > 0) S0 = (s / 32) * 32; }
  int S1 = ((t0 + 16 + 31) / 32) * 32; if (S1 > Tn) S1 = Tn;

  for (int c = S0; c < S1; c += 32) {
    __syncthreads();
    for (int i = tid; i < 32 * 64; i += 256) {
      int s = i >> 6, e = i & 63;
      size_t g = base + (size_t)(c + s) * HD + e;
      kv[s][e] = make_float2(kr[g], ki[g]);
      vv[s][e] = make_float2(vr[g], vi[g]);
    }
    __syncthreads();

    // -------- scores: lane = (key kslot, dim-half ehalf)
    float sr[4] = {0, 0, 0, 0}, si[4] = {0, 0, 0, 0};
#pragma unroll
    for (int e2 = 0; e2 < 16; ++e2) {
      int e = ehalf * 32 + e2 * 2;
      float4 kk = *(const float4*)&kv[kslot][e];   // kr_e, ki_e, kr_e+1, ki_e+1
#pragma unroll
      for (int q = 0; q < 4; ++q) {
        float4 qq = *(const float4*)&qsh[wq0 + q][e];
        sr[q] += qq.x * kk.x + qq.y * kk.y + qq.z * kk.z + qq.w * kk.w;
        si[q] += qq.y * kk.x - qq.x * kk.y + qq.w * kk.z - qq.z * kk.w;
      }
    }
#pragma unroll
    for (int q = 0; q < 4; ++q) {
      sr[q] += __shfl_xor(sr[q], 32);
      si[q] += __shfl_xor(si[q], 32);
    }

    const int sg = c + kslot;
#pragma unroll
    for (int q = 0; q < 4; ++q) {
      const int t = t0 + wq0 + q;
      bool valid = (sg <= t) && (t - sg < W);
      float srm = valid ? sr[q] * 0.125f : 0.f;   // scale = HD^-0.5 = 1/8
      float sim = valid ? si[q] * 0.125f : 0.f;
      float sab = sqrtf(srm * srm + sim * sim + CN_EPS);
      float cm = sab;
#pragma unroll
      for (int d = 16; d; d >>= 1) cm = fmaxf(cm, __shfl_xor(cm, d));
      float mn   = fmaxf(m[q], cm);
      float resc = expf(m[q] - mn);
      float p    = expf(sab - mn);
      float psum = p;
#pragma unroll
      for (int d = 16; d; d >>= 1) psum += __shfl_xor(psum, d);
      l[q]  = l[q] * resc + psum;
      ar_[q] *= resc; ai_[q] *= resc;
      m[q] = mn;
      if (ehalf == 0) ps[wq0 + q][kslot] = make_float2(p * srm, p * sim);
    }

    // -------- PV: lane = output dim e
#pragma unroll 8
    for (int s2 = 0; s2 < 32; ++s2) {
      float2 v2 = vv[s2][lane];
#pragma unroll
      for (int q = 0; q < 4; ++q) {
        float2 pp = ps[wq0 + q][s2];
        ar_[q] += pp.x * v2.y + pp.y * v2.x;   // A*(sr*vi + si*vr)
        ai_[q] += pp.y * v2.y - pp.x * v2.x;   // A*(si*vi - sr*vr)
      }
    }
  }

  const float mval = sqrtf(CN_EPS);
  const float rem  = (float)(Tn - (S1 - S0));
#pragma unroll
  for (int q = 0; q < 4; ++q) {
    const int t = t0 + wq0 + q;
    float lq  = l[q] + rem * expf(mval - m[q]);
    float inv = 1.f / lq;
    size_t o = ((size_t)b * Tn + t) * Dm + h * HD + lane;
    dzr[o] = ar_[q] * inv;
    dzi[o] = ai_[q] * inv;
  }
}

// ---------------------------------------------------------------- launcher

extern "C" void kernel_launch(void* const* d_in, const int* in_sizes, int n_in,
                              void* d_out, int out_size, void* d_ws, size_t ws_size,
                              hipStream_t stream) {
  const int*   idx   = (const int*)d_in[0];
  const float* wte   = (const float*)d_in[1];
  const float* Wq    = (const float*)d_in[2];
  const float* Wk    = (const float*)d_in[3];
  const float* Wv    = (const float*)d_in[4];
  const float* Wo    = (const float*)d_in[5];
  const float* Wfc   = (const float*)d_in[6];
  const float* Wproj = (const float*)d_in[7];
  const float* lmh   = (const float*)d_in[8];
  float* out = (float*)d_out;

  const size_t S = (size_t)BT * Dm;           // 1,572,864 floats
  // persistent state in ws (~24.3 MiB)
  float* ws   = (float*)d_ws;
  float* cosT = ws;
  float* sinT = ws + Tn * D2;
  float* xr   = ws + 2 * Tn * D2;
  float* xi   = xr + S;
  float* xrn  = xi + S;
  float* xin  = xrn + S;
  // transients in d_out (262 MB; all dead before the final GEMM overwrites d_out)
  float* scr = out;
  float* aqr = scr + 0 * S;   // pre-transpose QKV (cgemm outputs)
  float* aqi = scr + 1 * S;
  float* akr = scr + 2 * S;
  float* aki = scr + 3 * S;
  float* avr = scr + 4 * S;
  float* avi = scr + 5 * S;
  float* qR  = scr + 6 * S;   // post-transpose (B,NH,T,HD)
  float* qI  = scr + 7 * S;
  float* kR  = scr + 8 * S;
  float* kI  = scr + 9 * S;
  float* vR  = scr + 10 * S;
  float* vI  = scr + 11 * S;
  float* dzr = aqr;           // attention out (aq* dead after prep)
  float* dzi = aqi;
  float* rbuf  = scr + 2 * S;          // MLP |x|  (akr slot, dead)
  float* hbuf  = scr + 3 * S;          // MLP hidden, 4*S (aki..qR-1... spans 3S..7S? no: 3,4,5,6)
  float* delta = scr + 7 * S;          // MLP delta (qI slot, dead)

  const int elemGrid = (int)((S + 255) / 256);

  rope_tables_k<<<dim3(128), dim3(256), 0, stream>>>(cosT, sinT);
  embed_k<<<dim3(elemGrid), dim3(256), 0, stream>>>(idx, wte, xr, xi);

  for (int l = 0; l < 2; ++l) {
    const float* wq = Wq + (size_t)l * 2 * Dm * Dm;
    const float* wk = Wk + (size_t)l * 2 * Dm * Dm;
    const float* wv = Wv + (size_t)l * 2 * Dm * Dm;
    const float* wo = Wo + (size_t)l * Dm * Dm;
    const float* wfc = Wfc + (size_t)l * FF * Dm;
    const float* wpj = Wproj + (size_t)l * Dm * FF;
    const int W = (l == 0) ? 512 : 1024;

    cnorm_k<<<dim3(BT), dim3(256), 0, stream>>>(xr, xi, xrn, xin);

    cgemm_qkv_k<<<dim3(12, 32, 3), dim3(256), 0, stream>>>(
        xrn, xin, wq, wk, wv, aqr, aqi, akr, aki, avr, avi, BT, Dm, Dm);
    qkv_prep_k<<<dim3(BT * NHh / 4, 3), dim3(256), 0, stream>>>(
        aqr, aqi, akr, aki, avr, avi, qR, qI, kR, kI, vR, vI, cosT, sinT);

    attn_k<<<dim3(Bn * NHh, Tn / 16), dim3(256), 0, stream>>>(qR, qI, kR, kI, vR, vI, dzr, dzi, W);

    cgemm_nt_k<false, true><<<dim3(12, 32), dim3(256), 0, stream>>>(dzr, dzi, wo, xr, xi, BT, Dm, Dm);

    cnorm_k<<<dim3(BT), dim3(256), 0, stream>>>(xr, xi, xrn, xin);
    mlp_pre_k<<<dim3(elemGrid), dim3(256), 0, stream>>>(xrn, xin, rbuf);
    gemm_nt_k<1, false><<<dim3(24, 16), dim3(256), 0, stream>>>(rbuf, wfc, hbuf, BT, FF, Dm);
    gemm_nt_k<0, false><<<dim3(6, 16), dim3(256), 0, stream>>>(hbuf, wpj, delta, BT, Dm, FF);
    mlp_post_k<<<dim3(elemGrid), dim3(256), 0, stream>>>(rbuf, delta, xrn, xin, xr, xi);
  }

  cnorm_k<<<dim3(BT), dim3(256), 0, stream>>>(xr, xi, xrn, xin);
  gemm_nt_k<0, false><<<dim3(250, 16), dim3(256), 0, stream>>>(xrn, lmh, out, BT, 32000, Dm);
}

// Round 4
// 3911.866 us; speedup vs baseline: 1.2781x; 1.2781x over previous
//
#include <hip/hip_runtime.h>
#include <math.h>

constexpr int Bn = 2, Tn = 1024, NHh = 12, HD = 64, D2 = 32, Dm = 768, FF = 3072;
constexpr int BT = Bn * Tn;                 // 2048
constexpr float CN_EPS  = 1e-8f;
constexpr float RMS_EPS = 1.1920929e-07f;

typedef __attribute__((ext_vector_type(8))) short short8v;   // 8 bf16 (4 VGPR)
typedef __attribute__((ext_vector_type(4))) float f32x4;
typedef unsigned short ushort_t;
typedef unsigned int uint_t;

__device__ __forceinline__ ushort_t bf16h(float x) {
  union { float f; uint_t u; } c; c.f = x;
  uint_t u = c.u;
  uint_t r = (u + 0x7FFFu + ((u >> 16) & 1u)) >> 16;   // RNE
  return (ushort_t)r;
}
__device__ __forceinline__ float bf2f(ushort_t h) {
  union { uint_t u; float f; } c; c.u = ((uint_t)h) << 16;
  return c.f;
}

// ---------------------------------------------------------------- small kernels

__global__ void rope_tables_k(float* __restrict__ cosT, float* __restrict__ sinT) {
  int i = blockIdx.x * 256 + threadIdx.x;
  if (i < Tn * D2) {
    int t = i >> 5, j = i & 31;
    float inv = powf(10000.f, -(float)(2 * j) / (float)HD);
    float f = (float)t * inv;
    cosT[i] = cosf(f);
    sinT[i] = sinf(f);
  }
}

__global__ void embed_k(const int* __restrict__ idx, const float* __restrict__ wte,
                        float* __restrict__ xr, float* __restrict__ xi) {
  int i = blockIdx.x * 256 + threadIdx.x;
  if (i < BT * Dm) {
    int row = i / Dm, c = i - row * Dm;
    xr[i] = wte[(size_t)idx[row] * Dm + c];
    xi[i] = 0.f;
  }
}

// complex_norm over D: scale = rsqrt(mean(xr^2+xi^2) + CN_EPS + RMS_EPS)
__global__ __launch_bounds__(256) void cnorm_k(const float* __restrict__ xr, const float* __restrict__ xi,
                                               float* __restrict__ onr, float* __restrict__ oni) {
  int row = blockIdx.x;
  const float* pr = xr + (size_t)row * Dm;
  const float* pi = xi + (size_t)row * Dm;
  float a[3], b[3];
  float ss = 0.f;
#pragma unroll
  for (int j = 0; j < 3; ++j) {
    int c = threadIdx.x + j * 256;
    a[j] = pr[c]; b[j] = pi[c];
    ss += a[j] * a[j] + b[j] * b[j];
  }
#pragma unroll
  for (int d = 32; d; d >>= 1) ss += __shfl_xor(ss, d);
  __shared__ float red[4];
  int wave = threadIdx.x >> 6, lane = threadIdx.x & 63;
  if (lane == 0) red[wave] = ss;
  __syncthreads();
  float tot = red[0] + red[1] + red[2] + red[3];
  float inv = rsqrtf(tot * (1.f / Dm) + CN_EPS + RMS_EPS);
#pragma unroll
  for (int j = 0; j < 3; ++j) {
    int c = threadIdx.x + j * 256;
    onr[(size_t)row * Dm + c] = a[j] * inv;
    oni[(size_t)row * Dm + c] = b[j] * inv;
  }
}

// Batched QKV prep: rope(first half) + complex_norm over HD + transpose
// (B,T,D)->(B,NH,T,HD). blockIdx.y selects {0:q,1:k,2:v}; v skips rope+norm.
__global__ __launch_bounds__(256) void qkv_prep_k(
    const float* __restrict__ aqr, const float* __restrict__ aqi,
    const float* __restrict__ akr, const float* __restrict__ aki,
    const float* __restrict__ avr, const float* __restrict__ avi,
    float* __restrict__ qR, float* __restrict__ qI,
    float* __restrict__ kR, float* __restrict__ kI,
    float* __restrict__ vR, float* __restrict__ vI,
    const float* __restrict__ cosT, const float* __restrict__ sinT) {
  const int which = blockIdx.y;
  const float* inr = (which == 0) ? aqr : (which == 1) ? akr : avr;
  const float* ini = (which == 0) ? aqi : (which == 1) ? aki : avi;
  float* outr = (which == 0) ? qR : (which == 1) ? kR : vR;
  float* outi = (which == 0) ? qI : (which == 1) ? kI : vI;

  int gid  = blockIdx.x * 4 + (threadIdx.x >> 6);   // (b,t,h) item, one wave each
  int lane = threadIdx.x & 63;
  int h  = gid % NHh;
  int bt = gid / NHh;
  int t  = bt & (Tn - 1);
  int b  = bt >> 10;
  size_t src = (size_t)bt * Dm + h * HD + lane;
  float xr = inr[src], xi = ini[src];
  if (which != 2) {
    if (lane < D2) {
      float c = cosT[t * D2 + lane], s = sinT[t * D2 + lane];
      float nr = xr * c - xi * s;
      xi = xr * s + xi * c;
      xr = nr;
    }
    float ss = xr * xr + xi * xi;
#pragma unroll
    for (int d = 32; d; d >>= 1) ss += __shfl_xor(ss, d);
    float inv = rsqrtf(ss * (1.f / HD) + CN_EPS + RMS_EPS);
    xr *= inv; xi *= inv;
  }
  size_t dst = ((size_t)(b * NHh + h) * Tn + t) * HD + lane;
  outr[dst] = xr;
  outi[dst] = xi;
}

__global__ void mlp_pre_k(const float* __restrict__ xrn, const float* __restrict__ xin,
                          float* __restrict__ r) {
  int i = blockIdx.x * 256 + threadIdx.x;
  if (i < BT * Dm)
    r[i] = sqrtf(xrn[i] * xrn[i] + xin[i] * xin[i] + CN_EPS);
}

__global__ void mlp_post_k(const float* __restrict__ rb, const float* __restrict__ delta,
                           const float* __restrict__ xrn, const float* __restrict__ xin,
                           float* __restrict__ xr, float* __restrict__ xi) {
  int i = blockIdx.x * 256 + threadIdx.x;
  if (i < BT * Dm) {
    float r  = rb[i];
    float z  = r + delta[i];
    float rn = (z > 20.f) ? z : log1pf(expf(z));
    float s  = (rn - r) / r;
    xr[i] += xrn[i] * s;
    xi[i] += xin[i] * s;
  }
}

// ---------------------------------------------------------------- MFMA split-bf16 GEMM
// C = A(MxK) @ B(NxK)^T, fp32 in/out, near-fp32 accuracy via 3-term bf16 split:
// a*b ~= ah*bh + ah*bl + al*bh  (err ~2^-18 rel). 128x128 tile, BK=32,
// 256 thr = 4 waves (2x2), each wave 64x64 = 4x4 frags of 16x16x32 MFMA.
// K-permutation within the 32-block is irrelevant (same convention for A and B).
// Requires M%128==0, N%128==0, K%32==0.

template<int EPI>   // 0 none, 1 relu^2
__global__ __launch_bounds__(256, 2) void gemm_nt_mfma_k(
    const float* __restrict__ A, const float* __restrict__ B,
    float* __restrict__ C, int M, int N, int K) {
  __shared__ alignas(16) ushort_t Ahi[128][40];   // 32 cols + pad->40 (80B rows)
  __shared__ alignas(16) ushort_t Alo[128][40];
  __shared__ alignas(16) ushort_t Bhi[128][40];
  __shared__ alignas(16) ushort_t Blo[128][40];

  const int row0 = blockIdx.y * 128, col0 = blockIdx.x * 128;
  const int tid  = threadIdx.x;
  const int wave = tid >> 6, lane = tid & 63;
  const int wm = (wave >> 1) * 64, wn = (wave & 1) * 64;
  const int l15 = lane & 15, g = lane >> 4;

  f32x4 acc[4][4] = {};

  for (int k0 = 0; k0 < K; k0 += 32) {
    __syncthreads();
#pragma unroll
    for (int j = 0; j < 4; ++j) {
      int idx = tid + j * 256;            // 0..1023 over 128 rows x 8 float4
      int r = idx >> 3, c4 = (idx & 7) * 4;
      float4 av = *(const float4*)&A[(size_t)(row0 + r) * K + k0 + c4];
      float4 bv = *(const float4*)&B[(size_t)(col0 + r) * K + k0 + c4];
      float af[4] = {av.x, av.y, av.z, av.w};
      float bf[4] = {bv.x, bv.y, bv.z, bv.w};
      ushort_t ah[4], al[4], bh[4], bl[4];
#pragma unroll
      for (int e = 0; e < 4; ++e) {
        ah[e] = bf16h(af[e]); al[e] = bf16h(af[e] - bf2f(ah[e]));
        bh[e] = bf16h(bf[e]); bl[e] = bf16h(bf[e] - bf2f(bh[e]));
      }
#pragma unroll
      for (int e = 0; e < 4; ++e) {
        Ahi[r][c4 + e] = ah[e]; Alo[r][c4 + e] = al[e];
        Bhi[r][c4 + e] = bh[e]; Blo[r][c4 + e] = bl[e];
      }
    }
    __syncthreads();

    short8v a_hi[4], a_lo[4], b_hi[4], b_lo[4];
#pragma unroll
    for (int f = 0; f < 4; ++f) {
      a_hi[f] = *(const short8v*)&Ahi[wm + f * 16 + l15][g * 8];
      a_lo[f] = *(const short8v*)&Alo[wm + f * 16 + l15][g * 8];
      b_hi[f] = *(const short8v*)&Bhi[wn + f * 16 + l15][g * 8];
      b_lo[f] = *(const short8v*)&Blo[wn + f * 16 + l15][g * 8];
    }
#pragma unroll
    for (int i = 0; i < 4; ++i)
#pragma unroll
      for (int j = 0; j < 4; ++j) {
        acc[i][j] = __builtin_amdgcn_mfma_f32_16x16x32_bf16(a_hi[i], b_hi[j], acc[i][j], 0, 0, 0);
        acc[i][j] = __builtin_amdgcn_mfma_f32_16x16x32_bf16(a_hi[i], b_lo[j], acc[i][j], 0, 0, 0);
        acc[i][j] = __builtin_amdgcn_mfma_f32_16x16x32_bf16(a_lo[i], b_hi[j], acc[i][j], 0, 0, 0);
      }
  }

  // C/D layout (HW-verified): col = lane&15, row = (lane>>4)*4 + reg
#pragma unroll
  for (int i = 0; i < 4; ++i)
#pragma unroll
    for (int j = 0; j < 4; ++j)
#pragma unroll
      for (int r = 0; r < 4; ++r) {
        int rr = row0 + wm + i * 16 + g * 4 + r;
        int cc = col0 + wn + j * 16 + l15;
        float v = acc[i][j][r];
        if (EPI == 1) { v = fmaxf(v, 0.f); v = v * v; }
        C[(size_t)rr * N + cc] = v;
      }
}

// ---------------------------------------------------------------- complex GEMM (fp32 VALU)
// Or = Ar@Br^T - Ai@Bi^T, Oi = Ar@Bi^T + Ai@Br^T (CW; Bi at Bw+N*K)
// Or = Ar@Br^T,            Oi = Ai@Br^T          (!CW)
template<bool CW, bool ACC>
__device__ __forceinline__ void cgemm_body(const float* __restrict__ Ar, const float* __restrict__ Ai,
                                           const float* __restrict__ Bw,
                                           float* __restrict__ Cr, float* __restrict__ Ci,
                                           int M, int N, int K, int bx, int by) {
  __shared__ alignas(16) float Asr[16][68];
  __shared__ alignas(16) float Asi[16][68];
  __shared__ alignas(16) float Bsr[16][68];
  __shared__ alignas(16) float Bsi[16][68];
  const int row0 = by * 64, col0 = bx * 64;
  const int tid = threadIdx.x;
  const int tx = tid & 15, ty = tid >> 4;
  const int lr = tid >> 2, lk = (tid & 3) * 4;
  const float* Br = Bw;
  const float* Bi = Bw + (size_t)N * K;
  float acr[4][4] = {};
  float aci[4][4] = {};
  for (int k0 = 0; k0 < K; k0 += 16) {
    __syncthreads();
    {
      float4 a = *(const float4*)&Ar[(size_t)(row0 + lr) * K + k0 + lk];
      float4 b = *(const float4*)&Ai[(size_t)(row0 + lr) * K + k0 + lk];
      float4 c = *(const float4*)&Br[(size_t)(col0 + lr) * K + k0 + lk];
      Asr[lk + 0][lr] = a.x; Asr[lk + 1][lr] = a.y; Asr[lk + 2][lr] = a.z; Asr[lk + 3][lr] = a.w;
      Asi[lk + 0][lr] = b.x; Asi[lk + 1][lr] = b.y; Asi[lk + 2][lr] = b.z; Asi[lk + 3][lr] = b.w;
      Bsr[lk + 0][lr] = c.x; Bsr[lk + 1][lr] = c.y; Bsr[lk + 2][lr] = c.z; Bsr[lk + 3][lr] = c.w;
      if (CW) {
        float4 d = *(const float4*)&Bi[(size_t)(col0 + lr) * K + k0 + lk];
        Bsi[lk + 0][lr] = d.x; Bsi[lk + 1][lr] = d.y; Bsi[lk + 2][lr] = d.z; Bsi[lk + 3][lr] = d.w;
      }
    }
    __syncthreads();
#pragma unroll
    for (int kk = 0; kk < 16; ++kk) {
      float4 a4 = *(const float4*)&Asr[kk][ty * 4];
      float4 i4 = *(const float4*)&Asi[kk][ty * 4];
      float4 b4 = *(const float4*)&Bsr[kk][tx * 4];
      float arv[4] = {a4.x, a4.y, a4.z, a4.w};
      float aiv[4] = {i4.x, i4.y, i4.z, i4.w};
      float brv[4] = {b4.x, b4.y, b4.z, b4.w};
      if (CW) {
        float4 c4 = *(const float4*)&Bsi[kk][tx * 4];
        float biv[4] = {c4.x, c4.y, c4.z, c4.w};
#pragma unroll
        for (int i = 0; i < 4; ++i)
#pragma unroll
          for (int j = 0; j < 4; ++j) {
            acr[i][j] += arv[i] * brv[j] - aiv[i] * biv[j];
            aci[i][j] += arv[i] * biv[j] + aiv[i] * brv[j];
          }
      } else {
#pragma unroll
        for (int i = 0; i < 4; ++i)
#pragma unroll
          for (int j = 0; j < 4; ++j) {
            acr[i][j] += arv[i] * brv[j];
            aci[i][j] += aiv[i] * brv[j];
          }
      }
    }
  }
#pragma unroll
  for (int i = 0; i < 4; ++i)
#pragma unroll
    for (int j = 0; j < 4; ++j) {
      size_t o = (size_t)(row0 + ty * 4 + i) * N + col0 + tx * 4 + j;
      if (ACC) { Cr[o] += acr[i][j]; Ci[o] += aci[i][j]; }
      else     { Cr[o]  = acr[i][j]; Ci[o]  = aci[i][j]; }
    }
}

template<bool CW, bool ACC>
__global__ __launch_bounds__(256) void cgemm_nt_k(const float* __restrict__ Ar, const float* __restrict__ Ai,
                                                  const float* __restrict__ Bw,
                                                  float* __restrict__ Cr, float* __restrict__ Ci,
                                                  int M, int N, int K) {
  cgemm_body<CW, ACC>(Ar, Ai, Bw, Cr, Ci, M, N, K, blockIdx.x, blockIdx.y);
}

// Batched QKV complex GEMM: blockIdx.z selects {0:Wq,1:Wk,2:Wv} + its output pair.
__global__ __launch_bounds__(256) void cgemm_qkv_k(
    const float* __restrict__ Ar, const float* __restrict__ Ai,
    const float* __restrict__ Wq, const float* __restrict__ Wk, const float* __restrict__ Wv,
    float* __restrict__ qr, float* __restrict__ qi,
    float* __restrict__ kr, float* __restrict__ ki,
    float* __restrict__ vr, float* __restrict__ vi,
    int M, int N, int K) {
  const int z = blockIdx.z;
  const float* Bw = (z == 0) ? Wq : (z == 1) ? Wk : Wv;
  float* Cr = (z == 0) ? qr : (z == 1) ? kr : vr;
  float* Ci = (z == 0) ? qi : (z == 1) ? ki : vi;
  cgemm_body<true, false>(Ar, Ai, Bw, Cr, Ci, M, N, K, blockIdx.x, blockIdx.y);
}

// ---------------------------------------------------------------- attention (flash-style, complex scores)

__global__ __launch_bounds__(256) void attn_k(
    const float* __restrict__ qr, const float* __restrict__ qi,
    const float* __restrict__ kr, const float* __restrict__ ki,
    const float* __restrict__ vr, const float* __restrict__ vi,
    float* __restrict__ dzr, float* __restrict__ dzi, int W) {
  const int bh = blockIdx.x;          // b*NH + h
  const int t0 = blockIdx.y * 16;
  const int b = bh / NHh, h = bh % NHh;
  const int tid = threadIdx.x;
  const int wave = tid >> 6, lane = tid & 63;
  const int kslot = lane & 31, ehalf = lane >> 5;
  const int wq0 = wave * 4;

  __shared__ alignas(16) float2 kv[32][66];   // (kr,ki), padded row
  __shared__ alignas(16) float2 vv[32][64];   // (vr,vi)
  __shared__ alignas(16) float2 qsh[16][64];  // (qr,qi)
  __shared__ float2 ps[16][32];               // (p*sr, p*si) per (q,key)

  const size_t base = (size_t)bh * Tn * HD;

  for (int i = tid; i < 16 * 64; i += 256) {
    int q = i >> 6, e = i & 63;
    size_t g = base + (size_t)(t0 + q) * HD + e;
    qsh[q][e] = make_float2(qr[g], qi[g]);
  }

  float m[4], l[4], ar_[4], ai_[4];
#pragma unroll
  for (int q = 0; q < 4; ++q) { m[q] = -1e30f; l[q] = 0.f; ar_[q] = 0.f; ai_[q] = 0.f; }

  int S0 = 0;
  { int s = t0 - W + 1; if (s > 0) S0 = (s / 32) * 32; }
  int S1 = ((t0 + 16 + 31) / 32) * 32; if (S1 > Tn) S1 = Tn;

  for (int c = S0; c < S1; c += 32) {
    __syncthreads();
    for (int i = tid; i < 32 * 64; i += 256) {
      int s = i >> 6, e = i & 63;
      size_t g = base + (size_t)(c + s) * HD + e;
      kv[s][e] = make_float2(kr[g], ki[g]);
      vv[s][e] = make_float2(vr[g], vi[g]);
    }
    __syncthreads();

    float sr[4] = {0, 0, 0, 0}, si[4] = {0, 0, 0, 0};
#pragma unroll
    for (int e2 = 0; e2 < 16; ++e2) {
      int e = ehalf * 32 + e2 * 2;
      float4 kk = *(const float4*)&kv[kslot][e];
#pragma unroll
      for (int q = 0; q < 4; ++q) {
        float4 qq = *(const float4*)&qsh[wq0 + q][e];
        sr[q] += qq.x * kk.x + qq.y * kk.y + qq.z * kk.z + qq.w * kk.w;
        si[q] += qq.y * kk.x - qq.x * kk.y + qq.w * kk.z - qq.z * kk.w;
      }
    }
#pragma unroll
    for (int q = 0; q < 4; ++q) {
      sr[q] += __shfl_xor(sr[q], 32);
      si[q] += __shfl_xor(si[q], 32);
    }

    const int sg = c + kslot;
#pragma unroll
    for (int q = 0; q < 4; ++q) {
      const int t = t0 + wq0 + q;
      bool valid = (sg <= t) && (t - sg < W);
      float srm = valid ? sr[q] * 0.125f : 0.f;   // scale = HD^-0.5 = 1/8
      float sim = valid ? si[q] * 0.125f : 0.f;
      float sab = sqrtf(srm * srm + sim * sim + CN_EPS);
      float cm = sab;
#pragma unroll
      for (int d = 16; d; d >>= 1) cm = fmaxf(cm, __shfl_xor(cm, d));
      float mn   = fmaxf(m[q], cm);
      float resc = expf(m[q] - mn);
      float p    = expf(sab - mn);
      float psum = p;
#pragma unroll
      for (int d = 16; d; d >>= 1) psum += __shfl_xor(psum, d);
      l[q]  = l[q] * resc + psum;
      ar_[q] *= resc; ai_[q] *= resc;
      m[q] = mn;
      if (ehalf == 0) ps[wq0 + q][kslot] = make_float2(p * srm, p * sim);
    }

#pragma unroll 8
    for (int s2 = 0; s2 < 32; ++s2) {
      float2 v2 = vv[s2][lane];
#pragma unroll
      for (int q = 0; q < 4; ++q) {
        float2 pp = ps[wq0 + q][s2];
        ar_[q] += pp.x * v2.y + pp.y * v2.x;   // A*(sr*vi + si*vr)
        ai_[q] += pp.y * v2.y - pp.x * v2.x;   // A*(si*vi - sr*vr)
      }
    }
  }

  const float mval = sqrtf(CN_EPS);
  const float rem  = (float)(Tn - (S1 - S0));
#pragma unroll
  for (int q = 0; q < 4; ++q) {
    const int t = t0 + wq0 + q;
    float lq  = l[q] + rem * expf(mval - m[q]);
    float inv = 1.f / lq;
    size_t o = ((size_t)b * Tn + t) * Dm + h * HD + lane;
    dzr[o] = ar_[q] * inv;
    dzi[o] = ai_[q] * inv;
  }
}

// ---------------------------------------------------------------- launcher

extern "C" void kernel_launch(void* const* d_in, const int* in_sizes, int n_in,
                              void* d_out, int out_size, void* d_ws, size_t ws_size,
                              hipStream_t stream) {
  const int*   idx   = (const int*)d_in[0];
  const float* wte   = (const float*)d_in[1];
  const float* Wq    = (const float*)d_in[2];
  const float* Wk    = (const float*)d_in[3];
  const float* Wv    = (const float*)d_in[4];
  const float* Wo    = (const float*)d_in[5];
  const float* Wfc   = (const float*)d_in[6];
  const float* Wproj = (const float*)d_in[7];
  const float* lmh   = (const float*)d_in[8];
  float* out = (float*)d_out;

  const size_t S = (size_t)BT * Dm;           // 1,572,864 floats
  // persistent state in ws (~24.3 MiB)
  float* ws   = (float*)d_ws;
  float* cosT = ws;
  float* sinT = ws + Tn * D2;
  float* xr   = ws + 2 * Tn * D2;
  float* xi   = xr + S;
  float* xrn  = xi + S;
  float* xin  = xrn + S;
  // transients in d_out (262 MB; all dead before the final GEMM overwrites d_out)
  float* scr = out;
  float* aqr = scr + 0 * S;   // pre-transpose QKV (cgemm outputs)
  float* aqi = scr + 1 * S;
  float* akr = scr + 2 * S;
  float* aki = scr + 3 * S;
  float* avr = scr + 4 * S;
  float* avi = scr + 5 * S;
  float* qR  = scr + 6 * S;   // post-transpose (B,NH,T,HD)
  float* qI  = scr + 7 * S;
  float* kR  = scr + 8 * S;
  float* kI  = scr + 9 * S;
  float* vR  = scr + 10 * S;
  float* vI  = scr + 11 * S;
  float* dzr = aqr;           // attention out (aq* dead after prep)
  float* dzi = aqi;
  float* rbuf  = scr + 2 * S;          // MLP |x|  (akr slot, dead)
  float* hbuf  = scr + 3 * S;          // MLP hidden, 4*S (slots 3..6)
  float* delta = scr + 7 * S;          // MLP delta (qI slot, dead)

  const int elemGrid = (int)((S + 255) / 256);

  rope_tables_k<<<dim3(128), dim3(256), 0, stream>>>(cosT, sinT);
  embed_k<<<dim3(elemGrid), dim3(256), 0, stream>>>(idx, wte, xr, xi);

  for (int l = 0; l < 2; ++l) {
    const float* wq = Wq + (size_t)l * 2 * Dm * Dm;
    const float* wk = Wk + (size_t)l * 2 * Dm * Dm;
    const float* wv = Wv + (size_t)l * 2 * Dm * Dm;
    const float* wo = Wo + (size_t)l * Dm * Dm;
    const float* wfc = Wfc + (size_t)l * FF * Dm;
    const float* wpj = Wproj + (size_t)l * Dm * FF;
    const int W = (l == 0) ? 512 : 1024;

    cnorm_k<<<dim3(BT), dim3(256), 0, stream>>>(xr, xi, xrn, xin);

    cgemm_qkv_k<<<dim3(12, 32, 3), dim3(256), 0, stream>>>(
        xrn, xin, wq, wk, wv, aqr, aqi, akr, aki, avr, avi, BT, Dm, Dm);
    qkv_prep_k<<<dim3(BT * NHh / 4, 3), dim3(256), 0, stream>>>(
        aqr, aqi, akr, aki, avr, avi, qR, qI, kR, kI, vR, vI, cosT, sinT);

    attn_k<<<dim3(Bn * NHh, Tn / 16), dim3(256), 0, stream>>>(qR, qI, kR, kI, vR, vI, dzr, dzi, W);

    cgemm_nt_k<false, true><<<dim3(12, 32), dim3(256), 0, stream>>>(dzr, dzi, wo, xr, xi, BT, Dm, Dm);

    cnorm_k<<<dim3(BT), dim3(256), 0, stream>>>(xr, xi, xrn, xin);
    mlp_pre_k<<<dim3(elemGrid), dim3(256), 0, stream>>>(xrn, xin, rbuf);
    gemm_nt_mfma_k<1><<<dim3(24, 16), dim3(256), 0, stream>>>(rbuf, wfc, hbuf, BT, FF, Dm);
    gemm_nt_mfma_k<0><<<dim3(6, 16), dim3(256), 0, stream>>>(hbuf, wpj, delta, BT, Dm, FF);
    mlp_post_k<<<dim3(elemGrid), dim3(256), 0, stream>>>(rbuf, delta, xrn, xin, xr, xi);
  }

  cnorm_k<<<dim3(BT), dim3(256), 0, stream>>>(xr, xi, xrn, xin);
  gemm_nt_mfma_k<0><<<dim3(250, 16), dim3(256), 0, stream>>>(xrn, lmh, out, BT, 32000, Dm);
}